// Round 4
// baseline (4765.158 us; speedup 1.0000x reference)
//
#include <hip/hip_runtime.h>
#include <cstdint>
#include <cfloat>

typedef float v2f __attribute__((ext_vector_type(2)));

// Sample grid: round(linspace(0,63,16)) -- verified no .5 cases, fp32/fp64 agree.
__constant__ int c_smp[16] = {0,4,8,13,17,21,25,29,34,38,42,46,50,55,59,63};

// Problem constants
static constexpr int NB   = 32;    // batch
static constexpr int NC   = 64;    // C1 channels after unshuffle
static constexpr int NH   = 64;    // H1
static constexpr int NTOK = 4096;  // H1*W1
static constexpr int NM   = 256;   // samples
static constexpr int NK   = 3;     // neighbors

// ---------------------------------------------------------------------------
// Kernel 1: gather x_sample in two layouts. One block per (b, gi).
// ---------------------------------------------------------------------------
__global__ __launch_bounds__(256) void k_xs(const float* __restrict__ x,
                                            float* __restrict__ xs_t,
                                            float* __restrict__ xs_m) {
    __shared__ __align__(16) float rows[16][2][128];   // 16 KB
    int b = blockIdx.x >> 4, gi = blockIdx.x & 15;
    int hh = c_smp[gi];
    int t = threadIdx.x;
    const float* xb = x + (size_t)b * 16 * 128 * 128;
#pragma unroll
    for (int it = 0; it < 4; ++it) {
        int q = t + it * 256;          // 0..1023 float4 groups
        int c = q >> 6;
        int rem = q & 63;
        int sh = rem >> 5;
        int col = (rem & 31) * 4;
        float4 v = *(const float4*)(xb + ((size_t)c * 128 + (2 * hh + sh)) * 128 + col);
        *(float4*)&rows[c][sh][col] = v;
    }
    __syncthreads();
    // xs_t: thread t -> c1 = t>>2, gj group = (t&3)*4 .. +3
    {
        int c1 = t >> 2;
        int c = c1 >> 2, sh = (c1 >> 1) & 1, sw = c1 & 1;
        int gj0 = (t & 3) * 4;
        float4 v;
        v.x = rows[c][sh][2 * c_smp[gj0 + 0] + sw];
        v.y = rows[c][sh][2 * c_smp[gj0 + 1] + sw];
        v.z = rows[c][sh][2 * c_smp[gj0 + 2] + sw];
        v.w = rows[c][sh][2 * c_smp[gj0 + 3] + sw];
        *(float4*)&xs_t[((size_t)b * NC + c1) * NM + gi * 16 + gj0] = v;
    }
    // xs_m: thread t -> mloc = t>>4, c1 group = (t&15)*4 .. +3
    {
        int mloc = t >> 4, cg = t & 15;
        int w2 = 2 * c_smp[mloc];
        float4 v;
        v.x = rows[cg][0][w2];
        v.y = rows[cg][0][w2 + 1];
        v.z = rows[cg][1][w2];
        v.w = rows[cg][1][w2 + 1];
        *(float4*)&xs_m[((size_t)b * NM + gi * 16 + mloc) * NC + cg * 4] = v;
    }
}

// ---------------------------------------------------------------------------
// Kernel 2: Z[b][k][m][o] = sum_c w[o][c][k] * xs[b][m][c]
// ---------------------------------------------------------------------------
__global__ __launch_bounds__(64) void k_z(const float* __restrict__ xs_m,
                                          const float* __restrict__ w,
                                          float* __restrict__ Z) {
    int bid = blockIdx.x;            // NB*3*16
    int mg  = bid & 15;
    int k   = (bid >> 4) % 3;
    int b   = bid / 48;
    int o   = threadIdx.x;           // 64
    float wf[64];
#pragma unroll
    for (int c = 0; c < 64; ++c) wf[c] = w[((size_t)o * 64 + c) * 3 + k];
    const float* xb = xs_m + (size_t)b * NM * NC;
    float* zb = Z + ((size_t)b * 3 + k) * NM * NC;
    for (int mm = 0; mm < 16; ++mm) {
        int m = mg * 16 + mm;
        const float* xr = xb + (size_t)m * NC;   // wave-uniform address
        float acc = 0.f;
#pragma unroll
        for (int c = 0; c < 64; ++c) acc = fmaf(wf[c], xr[c], acc);
        zb[(size_t)m * NC + o] = acc;            // coalesced over o
    }
}

// ---------------------------------------------------------------------------
// Kernel 3: distances + top-3 selection.
// R4: (a) dot tile uses v_pk_fma_f32 via float2 ext-vectors (same fma chains,
// same order -> bitwise identical); (b) register software pipeline: chunk
// kc+1's global loads are issued AFTER the compute barrier so their ~L2
// latency hides under chunk kc's compute (issuing before a __syncthreads is
// defeated by the compiler's vmcnt(0) drain at s_barrier).
// __launch_bounds__(256,4) pins VGPR<=128 (4 waves/SIMD).
// ---------------------------------------------------------------------------
#define LESS_E(ad, am, bd, bm) ((ad) < (bd) || ((ad) == (bd) && (am) < (bm)))
#define INSERT_E(xd, xm)                                                        \
    do {                                                                        \
        float _xd = (xd); int _xm = (xm);                                       \
        if (LESS_E(_xd, _xm, e2d, e2m)) {                                       \
            e2d = _xd; e2m = _xm;                                               \
            if (LESS_E(e2d, e2m, e1d, e1m)) {                                   \
                float td = e1d; int tm = e1m; e1d = e2d; e1m = e2m;             \
                e2d = td; e2m = tm;                                             \
                if (LESS_E(e1d, e1m, e0d, e0m)) {                               \
                    float sd = e0d; int sm = e0m; e0d = e1d; e0m = e1m;         \
                    e1d = sd; e1m = sm;                                         \
                }                                                               \
            }                                                                   \
        }                                                                       \
    } while (0)

__global__ __launch_bounds__(256, 4) void k_dist(const float* __restrict__ x,
                                                 const float* __restrict__ xs_t,
                                                 int* __restrict__ idx) {
    __shared__ __align__(16) float att[16][64];    // 4 KB   A chunk [c][n]
    __shared__ __align__(16) float xsB[16][256];   // 16 KB  B chunk [c][perm(m)]
    __shared__ float m2l[256];
    __shared__ float n2l[64];

    int b = blockIdx.x >> 6;
    int h = blockIdx.x & 63;
    int t = threadIdx.x;
    int r = t >> 5, cl = t & 31;

    v2f acc2[8][4];
#pragma unroll
    for (int i = 0; i < 8; ++i)
#pragma unroll
        for (int j = 0; j < 4; ++j) acc2[i][j] = (v2f)(0.f);

    float m2acc = 0.f, n2acc = 0.f;
    const float* xb = x + (size_t)b * 16 * 128 * 128;
    const float* xsb = xs_t + (size_t)b * NC * NM;

    // --- staging address helpers (recomputed per chunk; cheap VALU) ---
    // A: thread handles i = t, t+256  -> p=i>>6 (0..7), wcol=i&63
    // B: thread handles g = t + it*256, it=0..3 -> row=g>>6, m4=(g&63)*4
    float2 pre_a[2];
    float4 pre_b[4];

    // prefetch chunk 0
#pragma unroll
    for (int it = 0; it < 2; ++it) {
        int i = t + it * 256;
        int p = i >> 6, wcol = i & 63;
        int c1e = p * 2;                       // kc = 0
        int c = c1e >> 2, sh = (c1e >> 1) & 1;
        pre_a[it] = *(const float2*)(xb + ((size_t)c * 128 + (2 * h + sh)) * 128 + 2 * wcol);
    }
#pragma unroll
    for (int it = 0; it < 4; ++it) {
        int g = t + it * 256;
        int row = g >> 6, m4 = (g & 63) * 4;
        pre_b[it] = *(const float4*)&xsb[(size_t)row * NM + m4];   // kc = 0
    }

#pragma unroll
    for (int kc = 0; kc < 4; ++kc) {
        __syncthreads();   // previous compute done reading LDS
        // store prefetched regs to LDS
#pragma unroll
        for (int it = 0; it < 2; ++it) {
            int i = t + it * 256;
            int p = i >> 6, wcol = i & 63;
            att[p * 2 + 0][wcol] = pre_a[it].x;
            att[p * 2 + 1][wcol] = pre_a[it].y;
        }
#pragma unroll
        for (int it = 0; it < 4; ++it) {
            int g = t + it * 256;
            int row = g >> 6, m4 = (g & 63) * 4;
            int dst = ((m4 & 4) ? 128 : 0) + (m4 >> 3) * 4;
            *(float4*)&xsB[row][dst] = pre_b[it];
        }
        __syncthreads();

        // issue next chunk's loads NOW: latency hides under this chunk's compute
        if (kc < 3) {
#pragma unroll
            for (int it = 0; it < 2; ++it) {
                int i = t + it * 256;
                int p = i >> 6, wcol = i & 63;
                int c1e = (kc + 1) * 16 + p * 2;
                int c = c1e >> 2, sh = (c1e >> 1) & 1;
                pre_a[it] = *(const float2*)(xb + ((size_t)c * 128 + (2 * h + sh)) * 128 + 2 * wcol);
            }
#pragma unroll
            for (int it = 0; it < 4; ++it) {
                int g = t + it * 256;
                int row = g >> 6, m4 = (g & 63) * 4;
                pre_b[it] = *(const float4*)&xsb[(size_t)((kc + 1) * 16 + row) * NM + m4];
            }
        }

        // m2 / n2 partials (sequential ascending c, mul then add like np).
#pragma unroll
        for (int c = 0; c < 16; ++c) {
            float v = xsB[c][t];
            m2acc = __fadd_rn(m2acc, __fmul_rn(v, v));
        }
        if (t < 64) {
#pragma unroll
            for (int c = 0; c < 16; ++c) {
                float v = att[c][t];
                n2acc = __fadd_rn(n2acc, __fmul_rn(v, v));
            }
        }

        // dot accumulation: 8 tokens x 4 sample-pairs, v_pk_fma_f32.
#pragma unroll
        for (int k = 0; k < 16; ++k) {
            v2f b0 = *(const v2f*)&xsB[k][cl * 4];          // samples m0,m1
            v2f b1 = *(const v2f*)&xsB[k][cl * 4 + 2];      // m2,m3
            v2f b2 = *(const v2f*)&xsB[k][128 + cl * 4];    // m4,m5
            v2f b3 = *(const v2f*)&xsB[k][128 + cl * 4 + 2];// m6,m7
            float4 a0 = *(const float4*)&att[k][r * 8];
            float4 a1 = *(const float4*)&att[k][r * 8 + 4];
            float aa[8] = {a0.x, a0.y, a0.z, a0.w, a1.x, a1.y, a1.z, a1.w};
#pragma unroll
            for (int i = 0; i < 8; ++i) {
                v2f ai = {aa[i], aa[i]};
                acc2[i][0] = __builtin_elementwise_fma(ai, b0, acc2[i][0]);
                acc2[i][1] = __builtin_elementwise_fma(ai, b1, acc2[i][1]);
                acc2[i][2] = __builtin_elementwise_fma(ai, b2, acc2[i][2]);
                acc2[i][3] = __builtin_elementwise_fma(ai, b3, acc2[i][3]);
            }
        }
    }

    // inverse column permutation for the m2 store
    {
        int half = t >> 7, a = (t & 127) >> 2, j = t & 3;
        m2l[a * 8 + half * 4 + j] = m2acc;
    }
    if (t < 64) n2l[t] = n2acc;
    __syncthreads();

    // preload this thread's 8 m2 values once
    float m2r[8];
#pragma unroll
    for (int j = 0; j < 8; ++j) m2r[j] = m2l[cl * 8 + j];

    // selection — fully unrolled so acc stays in VGPRs.
#pragma unroll
    for (int i = 0; i < 8; ++i) {
        int nloc = r * 8 + i;
        float n2v = n2l[nloc];
        float e0d = FLT_MAX, e1d = FLT_MAX, e2d = FLT_MAX;
        int e0m = 0x7fffffff, e1m = 0x7fffffff, e2m = 0x7fffffff;
#pragma unroll
        for (int j = 0; j < 8; ++j) {
            int m = cl * 8 + j;
            float dv = acc2[i][j >> 1][j & 1];
            float t1 = __fadd_rn(n2v, m2r[j]);          // n2 + m2
            float d = __fadd_rn(t1, -2.0f * dv);        // - 2*dot (2*acc exact)
            INSERT_E(d, m);
        }
#pragma unroll
        for (int mask = 1; mask <= 16; mask <<= 1) {
            float f0 = __shfl_xor(e0d, mask); int g0 = __shfl_xor(e0m, mask);
            float f1 = __shfl_xor(e1d, mask); int g1 = __shfl_xor(e1m, mask);
            float f2 = __shfl_xor(e2d, mask); int g2 = __shfl_xor(e2m, mask);
            INSERT_E(f0, g0);
            INSERT_E(f1, g1);
            INSERT_E(f2, g2);
        }
        if (cl == 0) {
            int n = h * 64 + nloc;
            int* op = idx + ((size_t)b * NTOK + n) * NK;
            op[0] = e0m; op[1] = e1m; op[2] = e2m;
        }
    }
}

// ---------------------------------------------------------------------------
// Kernel 4: out = bias + Z[...,idx0,:] + Z[...,idx1,:] + Z[...,idx2,:],
// pixel-shuffled.
// ---------------------------------------------------------------------------
__global__ __launch_bounds__(256) void k_out(const float* __restrict__ Z,
                                             const int* __restrict__ idx,
                                             const float* __restrict__ bias,
                                             float* __restrict__ out) {
    __shared__ float staged[64 * 65];
    int b = blockIdx.x >> 6, h = blockIdx.x & 63;
    int t = threadIdx.x;
    int o = t & 63, wv = t >> 6;
    float bv = bias[o];
    const float* zb = Z + (size_t)b * 3 * NM * NC;
    const int* ib = idx + (size_t)b * NTOK * NK;
    for (int ti = 0; ti < 16; ++ti) {
        int w = wv * 16 + ti;
        int n = h * 64 + w;
        const int* ip = ib + (size_t)n * NK;       // wave-uniform
        int i0 = ip[0], i1 = ip[1], i2 = ip[2];
        float v = bv + zb[(size_t)i0 * NC + o]
                     + zb[(size_t)(NM + i1) * NC + o]
                     + zb[(size_t)(2 * NM + i2) * NC + o];
        staged[o * 65 + w] = v;                    // (o+w)%32 banks: conflict-free
    }
    __syncthreads();
    float* ob = out + (size_t)b * 16 * 128 * 128;
#pragma unroll
    for (int it = 0; it < 16; ++it) {
        int flat = t + it * 256;                   // 0..4095
        int W = flat & 127, sh = (flat >> 7) & 1, cc = flat >> 8;
        int oo = cc * 4 + sh * 2 + (W & 1);
        ob[((size_t)cc * 128 + 2 * h + sh) * 128 + W] = staged[oo * 65 + (W >> 1)];
    }
}

// ---------------------------------------------------------------------------
extern "C" void kernel_launch(void* const* d_in, const int* in_sizes, int n_in,
                              void* d_out, int out_size, void* d_ws, size_t ws_size,
                              hipStream_t stream) {
    const float* x    = (const float*)d_in[0];
    const float* w    = (const float*)d_in[1];
    const float* bias = (const float*)d_in[2];
    float* out = (float*)d_out;
    float* ws  = (float*)d_ws;

    // workspace layout (floats):
    float* xs_t = ws;                          // 32*64*256   = 524288
    float* xs_m = ws + 524288;                 // 32*256*64   = 524288
    float* Z    = ws + 1048576;                // 32*3*256*64 = 1572864
    int*   idxb = (int*)(ws + 2621440);        // 32*4096*3   = 393216 ints
    // total ~12 MB

    hipLaunchKernelGGL(k_xs,   dim3(NB * 16),     dim3(256), 0, stream, x, xs_t, xs_m);
    hipLaunchKernelGGL(k_z,    dim3(NB * 3 * 16), dim3(64),  0, stream, xs_m, w, Z);
    hipLaunchKernelGGL(k_dist, dim3(NB * 64),     dim3(256), 0, stream, x, xs_t, idxb);
    hipLaunchKernelGGL(k_out,  dim3(NB * 64),     dim3(256), 0, stream, Z, idxb, bias, out);
}

// Round 5
// 3370.079 us; speedup vs baseline: 1.4140x; 1.4140x over previous
//
#include <hip/hip_runtime.h>
#include <cstdint>
#include <cfloat>

typedef float v2f __attribute__((ext_vector_type(2)));

// Sample grid: round(linspace(0,63,16)) -- verified no .5 cases, fp32/fp64 agree.
__constant__ int c_smp[16] = {0,4,8,13,17,21,25,29,34,38,42,46,50,55,59,63};

// Problem constants
static constexpr int NB   = 32;    // batch
static constexpr int NC   = 64;    // C1 channels after unshuffle
static constexpr int NH   = 64;    // H1
static constexpr int NTOK = 4096;  // H1*W1
static constexpr int NM   = 256;   // samples
static constexpr int NK   = 3;     // neighbors

// ---------------------------------------------------------------------------
// Kernel 1: gather x_sample in two layouts. One block per (b, gi).
// ---------------------------------------------------------------------------
__global__ __launch_bounds__(256) void k_xs(const float* __restrict__ x,
                                            float* __restrict__ xs_t,
                                            float* __restrict__ xs_m) {
    __shared__ __align__(16) float rows[16][2][128];   // 16 KB
    int b = blockIdx.x >> 4, gi = blockIdx.x & 15;
    int hh = c_smp[gi];
    int t = threadIdx.x;
    const float* xb = x + (size_t)b * 16 * 128 * 128;
#pragma unroll
    for (int it = 0; it < 4; ++it) {
        int q = t + it * 256;          // 0..1023 float4 groups
        int c = q >> 6;
        int rem = q & 63;
        int sh = rem >> 5;
        int col = (rem & 31) * 4;
        float4 v = *(const float4*)(xb + ((size_t)c * 128 + (2 * hh + sh)) * 128 + col);
        *(float4*)&rows[c][sh][col] = v;
    }
    __syncthreads();
    // xs_t: thread t -> c1 = t>>2, gj group = (t&3)*4 .. +3
    {
        int c1 = t >> 2;
        int c = c1 >> 2, sh = (c1 >> 1) & 1, sw = c1 & 1;
        int gj0 = (t & 3) * 4;
        float4 v;
        v.x = rows[c][sh][2 * c_smp[gj0 + 0] + sw];
        v.y = rows[c][sh][2 * c_smp[gj0 + 1] + sw];
        v.z = rows[c][sh][2 * c_smp[gj0 + 2] + sw];
        v.w = rows[c][sh][2 * c_smp[gj0 + 3] + sw];
        *(float4*)&xs_t[((size_t)b * NC + c1) * NM + gi * 16 + gj0] = v;
    }
    // xs_m: thread t -> mloc = t>>4, c1 group = (t&15)*4 .. +3
    {
        int mloc = t >> 4, cg = t & 15;
        int w2 = 2 * c_smp[mloc];
        float4 v;
        v.x = rows[cg][0][w2];
        v.y = rows[cg][0][w2 + 1];
        v.z = rows[cg][1][w2];
        v.w = rows[cg][1][w2 + 1];
        *(float4*)&xs_m[((size_t)b * NM + gi * 16 + mloc) * NC + cg * 4] = v;
    }
}

// ---------------------------------------------------------------------------
// Kernel 2: Z[b][k][m][o] = sum_c w[o][c][k] * xs[b][m][c]
// ---------------------------------------------------------------------------
__global__ __launch_bounds__(64) void k_z(const float* __restrict__ xs_m,
                                          const float* __restrict__ w,
                                          float* __restrict__ Z) {
    int bid = blockIdx.x;            // NB*3*16
    int mg  = bid & 15;
    int k   = (bid >> 4) % 3;
    int b   = bid / 48;
    int o   = threadIdx.x;           // 64
    float wf[64];
#pragma unroll
    for (int c = 0; c < 64; ++c) wf[c] = w[((size_t)o * 64 + c) * 3 + k];
    const float* xb = xs_m + (size_t)b * NM * NC;
    float* zb = Z + ((size_t)b * 3 + k) * NM * NC;
    for (int mm = 0; mm < 16; ++mm) {
        int m = mg * 16 + mm;
        const float* xr = xb + (size_t)m * NC;   // wave-uniform address
        float acc = 0.f;
#pragma unroll
        for (int c = 0; c < 64; ++c) acc = fmaf(wf[c], xr[c], acc);
        zb[(size_t)m * NC + o] = acc;            // coalesced over o
    }
}

// ---------------------------------------------------------------------------
// Kernel 3: distances + top-3 selection.
// R5 = R4 structure with the __launch_bounds__ min-waves pin REMOVED.
// R4 post-mortem: (256,4) made the compiler clamp to VGPR=64 -> the 64-reg
// acc2 tile spilled to scratch inside the fma loop (FETCH 25 MB -> 10.9 GB,
// VALUBusy 2%). Plain (256) gave VGPR=108, zero spill in R3.
//   (a) dot tile uses v_pk_fma_f32 via float2 ext-vectors (same fma chains,
//       same order -> bitwise identical to R3);
//   (b) register software pipeline: chunk kc+1's global loads issued AFTER
//       the compute barrier so L2 latency hides under chunk kc's compute.
// ---------------------------------------------------------------------------
#define LESS_E(ad, am, bd, bm) ((ad) < (bd) || ((ad) == (bd) && (am) < (bm)))
#define INSERT_E(xd, xm)                                                        \
    do {                                                                        \
        float _xd = (xd); int _xm = (xm);                                       \
        if (LESS_E(_xd, _xm, e2d, e2m)) {                                       \
            e2d = _xd; e2m = _xm;                                               \
            if (LESS_E(e2d, e2m, e1d, e1m)) {                                   \
                float td = e1d; int tm = e1m; e1d = e2d; e1m = e2m;             \
                e2d = td; e2m = tm;                                             \
                if (LESS_E(e1d, e1m, e0d, e0m)) {                               \
                    float sd = e0d; int sm = e0m; e0d = e1d; e0m = e1m;         \
                    e1d = sd; e1m = sm;                                         \
                }                                                               \
            }                                                                   \
        }                                                                       \
    } while (0)

__global__ __launch_bounds__(256) void k_dist(const float* __restrict__ x,
                                              const float* __restrict__ xs_t,
                                              int* __restrict__ idx) {
    __shared__ __align__(16) float att[16][64];    // 4 KB   A chunk [c][n]
    __shared__ __align__(16) float xsB[16][256];   // 16 KB  B chunk [c][perm(m)]
    __shared__ float m2l[256];
    __shared__ float n2l[64];

    int b = blockIdx.x >> 6;
    int h = blockIdx.x & 63;
    int t = threadIdx.x;
    int r = t >> 5, cl = t & 31;

    v2f acc2[8][4];
#pragma unroll
    for (int i = 0; i < 8; ++i)
#pragma unroll
        for (int j = 0; j < 4; ++j) acc2[i][j] = (v2f)(0.f);

    float m2acc = 0.f, n2acc = 0.f;
    const float* xb = x + (size_t)b * 16 * 128 * 128;
    const float* xsb = xs_t + (size_t)b * NC * NM;

    float2 pre_a[2];
    float4 pre_b[4];

    // prefetch chunk 0
#pragma unroll
    for (int it = 0; it < 2; ++it) {
        int i = t + it * 256;
        int p = i >> 6, wcol = i & 63;
        int c1e = p * 2;                       // kc = 0
        int c = c1e >> 2, sh = (c1e >> 1) & 1;
        pre_a[it] = *(const float2*)(xb + ((size_t)c * 128 + (2 * h + sh)) * 128 + 2 * wcol);
    }
#pragma unroll
    for (int it = 0; it < 4; ++it) {
        int g = t + it * 256;
        int row = g >> 6, m4 = (g & 63) * 4;
        pre_b[it] = *(const float4*)&xsb[(size_t)row * NM + m4];   // kc = 0
    }

#pragma unroll
    for (int kc = 0; kc < 4; ++kc) {
        __syncthreads();   // previous compute done reading LDS
        // store prefetched regs to LDS
#pragma unroll
        for (int it = 0; it < 2; ++it) {
            int i = t + it * 256;
            int p = i >> 6, wcol = i & 63;
            att[p * 2 + 0][wcol] = pre_a[it].x;
            att[p * 2 + 1][wcol] = pre_a[it].y;
        }
#pragma unroll
        for (int it = 0; it < 4; ++it) {
            int g = t + it * 256;
            int row = g >> 6, m4 = (g & 63) * 4;
            int dst = ((m4 & 4) ? 128 : 0) + (m4 >> 3) * 4;
            *(float4*)&xsB[row][dst] = pre_b[it];
        }
        __syncthreads();

        // issue next chunk's loads NOW: latency hides under this chunk's compute
        if (kc < 3) {
#pragma unroll
            for (int it = 0; it < 2; ++it) {
                int i = t + it * 256;
                int p = i >> 6, wcol = i & 63;
                int c1e = (kc + 1) * 16 + p * 2;
                int c = c1e >> 2, sh = (c1e >> 1) & 1;
                pre_a[it] = *(const float2*)(xb + ((size_t)c * 128 + (2 * h + sh)) * 128 + 2 * wcol);
            }
#pragma unroll
            for (int it = 0; it < 4; ++it) {
                int g = t + it * 256;
                int row = g >> 6, m4 = (g & 63) * 4;
                pre_b[it] = *(const float4*)&xsb[(size_t)((kc + 1) * 16 + row) * NM + m4];
            }
        }

        // m2 / n2 partials (sequential ascending c, mul then add like np).
#pragma unroll
        for (int c = 0; c < 16; ++c) {
            float v = xsB[c][t];
            m2acc = __fadd_rn(m2acc, __fmul_rn(v, v));
        }
        if (t < 64) {
#pragma unroll
            for (int c = 0; c < 16; ++c) {
                float v = att[c][t];
                n2acc = __fadd_rn(n2acc, __fmul_rn(v, v));
            }
        }

        // dot accumulation: 8 tokens x 4 sample-pairs, v_pk_fma_f32.
#pragma unroll
        for (int k = 0; k < 16; ++k) {
            v2f b0 = *(const v2f*)&xsB[k][cl * 4];          // samples m0,m1
            v2f b1 = *(const v2f*)&xsB[k][cl * 4 + 2];      // m2,m3
            v2f b2 = *(const v2f*)&xsB[k][128 + cl * 4];    // m4,m5
            v2f b3 = *(const v2f*)&xsB[k][128 + cl * 4 + 2];// m6,m7
            float4 a0 = *(const float4*)&att[k][r * 8];
            float4 a1 = *(const float4*)&att[k][r * 8 + 4];
            float aa[8] = {a0.x, a0.y, a0.z, a0.w, a1.x, a1.y, a1.z, a1.w};
#pragma unroll
            for (int i = 0; i < 8; ++i) {
                v2f ai = {aa[i], aa[i]};
                acc2[i][0] = __builtin_elementwise_fma(ai, b0, acc2[i][0]);
                acc2[i][1] = __builtin_elementwise_fma(ai, b1, acc2[i][1]);
                acc2[i][2] = __builtin_elementwise_fma(ai, b2, acc2[i][2]);
                acc2[i][3] = __builtin_elementwise_fma(ai, b3, acc2[i][3]);
            }
        }
    }

    // inverse column permutation for the m2 store
    {
        int half = t >> 7, a = (t & 127) >> 2, j = t & 3;
        m2l[a * 8 + half * 4 + j] = m2acc;
    }
    if (t < 64) n2l[t] = n2acc;
    __syncthreads();

    // preload this thread's 8 m2 values once
    float m2r[8];
#pragma unroll
    for (int j = 0; j < 8; ++j) m2r[j] = m2l[cl * 8 + j];

    // selection — fully unrolled so acc stays in VGPRs.
#pragma unroll
    for (int i = 0; i < 8; ++i) {
        int nloc = r * 8 + i;
        float n2v = n2l[nloc];
        float e0d = FLT_MAX, e1d = FLT_MAX, e2d = FLT_MAX;
        int e0m = 0x7fffffff, e1m = 0x7fffffff, e2m = 0x7fffffff;
#pragma unroll
        for (int j = 0; j < 8; ++j) {
            int m = cl * 8 + j;
            float dv = acc2[i][j >> 1][j & 1];
            float t1 = __fadd_rn(n2v, m2r[j]);          // n2 + m2
            float d = __fadd_rn(t1, -2.0f * dv);        // - 2*dot (2*acc exact)
            INSERT_E(d, m);
        }
#pragma unroll
        for (int mask = 1; mask <= 16; mask <<= 1) {
            float f0 = __shfl_xor(e0d, mask); int g0 = __shfl_xor(e0m, mask);
            float f1 = __shfl_xor(e1d, mask); int g1 = __shfl_xor(e1m, mask);
            float f2 = __shfl_xor(e2d, mask); int g2 = __shfl_xor(e2m, mask);
            INSERT_E(f0, g0);
            INSERT_E(f1, g1);
            INSERT_E(f2, g2);
        }
        if (cl == 0) {
            int n = h * 64 + nloc;
            int* op = idx + ((size_t)b * NTOK + n) * NK;
            op[0] = e0m; op[1] = e1m; op[2] = e2m;
        }
    }
}

// ---------------------------------------------------------------------------
// Kernel 4: out = bias + Z[...,idx0,:] + Z[...,idx1,:] + Z[...,idx2,:],
// pixel-shuffled.
// ---------------------------------------------------------------------------
__global__ __launch_bounds__(256) void k_out(const float* __restrict__ Z,
                                             const int* __restrict__ idx,
                                             const float* __restrict__ bias,
                                             float* __restrict__ out) {
    __shared__ float staged[64 * 65];
    int b = blockIdx.x >> 6, h = blockIdx.x & 63;
    int t = threadIdx.x;
    int o = t & 63, wv = t >> 6;
    float bv = bias[o];
    const float* zb = Z + (size_t)b * 3 * NM * NC;
    const int* ib = idx + (size_t)b * NTOK * NK;
    for (int ti = 0; ti < 16; ++ti) {
        int w = wv * 16 + ti;
        int n = h * 64 + w;
        const int* ip = ib + (size_t)n * NK;       // wave-uniform
        int i0 = ip[0], i1 = ip[1], i2 = ip[2];
        float v = bv + zb[(size_t)i0 * NC + o]
                     + zb[(size_t)(NM + i1) * NC + o]
                     + zb[(size_t)(2 * NM + i2) * NC + o];
        staged[o * 65 + w] = v;                    // (o+w)%32 banks: conflict-free
    }
    __syncthreads();
    float* ob = out + (size_t)b * 16 * 128 * 128;
#pragma unroll
    for (int it = 0; it < 16; ++it) {
        int flat = t + it * 256;                   // 0..4095
        int W = flat & 127, sh = (flat >> 7) & 1, cc = flat >> 8;
        int oo = cc * 4 + sh * 2 + (W & 1);
        ob[((size_t)cc * 128 + 2 * h + sh) * 128 + W] = staged[oo * 65 + (W >> 1)];
    }
}

// ---------------------------------------------------------------------------
extern "C" void kernel_launch(void* const* d_in, const int* in_sizes, int n_in,
                              void* d_out, int out_size, void* d_ws, size_t ws_size,
                              hipStream_t stream) {
    const float* x    = (const float*)d_in[0];
    const float* w    = (const float*)d_in[1];
    const float* bias = (const float*)d_in[2];
    float* out = (float*)d_out;
    float* ws  = (float*)d_ws;

    // workspace layout (floats):
    float* xs_t = ws;                          // 32*64*256   = 524288
    float* xs_m = ws + 524288;                 // 32*256*64   = 524288
    float* Z    = ws + 1048576;                // 32*3*256*64 = 1572864
    int*   idxb = (int*)(ws + 2621440);        // 32*4096*3   = 393216 ints
    // total ~12 MB

    hipLaunchKernelGGL(k_xs,   dim3(NB * 16),     dim3(256), 0, stream, x, xs_t, xs_m);
    hipLaunchKernelGGL(k_z,    dim3(NB * 3 * 16), dim3(64),  0, stream, xs_m, w, Z);
    hipLaunchKernelGGL(k_dist, dim3(NB * 64),     dim3(256), 0, stream, x, xs_t, idxb);
    hipLaunchKernelGGL(k_out,  dim3(NB * 64),     dim3(256), 0, stream, Z, idxb, bias, out);
}

// Round 6
// 237.283 us; speedup vs baseline: 20.0822x; 14.2028x over previous
//
#include <hip/hip_runtime.h>
#include <cstdint>
#include <cfloat>

typedef float v2f __attribute__((ext_vector_type(2)));

// Sample grid: round(linspace(0,63,16)) -- verified no .5 cases, fp32/fp64 agree.
__constant__ int c_smp[16] = {0,4,8,13,17,21,25,29,34,38,42,46,50,55,59,63};

// Problem constants
static constexpr int NB   = 32;    // batch
static constexpr int NC   = 64;    // C1 channels after unshuffle
static constexpr int NH   = 64;    // H1
static constexpr int NTOK = 4096;  // H1*W1
static constexpr int NM   = 256;   // samples
static constexpr int NK   = 3;     // neighbors

// ---------------------------------------------------------------------------
// Kernel 1: gather x_sample in two layouts. One block per (b, gi).
// ---------------------------------------------------------------------------
__global__ __launch_bounds__(256) void k_xs(const float* __restrict__ x,
                                            float* __restrict__ xs_t,
                                            float* __restrict__ xs_m) {
    __shared__ __align__(16) float rows[16][2][128];   // 16 KB
    int b = blockIdx.x >> 4, gi = blockIdx.x & 15;
    int hh = c_smp[gi];
    int t = threadIdx.x;
    const float* xb = x + (size_t)b * 16 * 128 * 128;
#pragma unroll
    for (int it = 0; it < 4; ++it) {
        int q = t + it * 256;          // 0..1023 float4 groups
        int c = q >> 6;
        int rem = q & 63;
        int sh = rem >> 5;
        int col = (rem & 31) * 4;
        float4 v = *(const float4*)(xb + ((size_t)c * 128 + (2 * hh + sh)) * 128 + col);
        *(float4*)&rows[c][sh][col] = v;
    }
    __syncthreads();
    // xs_t: thread t -> c1 = t>>2, gj group = (t&3)*4 .. +3
    {
        int c1 = t >> 2;
        int c = c1 >> 2, sh = (c1 >> 1) & 1, sw = c1 & 1;
        int gj0 = (t & 3) * 4;
        float4 v;
        v.x = rows[c][sh][2 * c_smp[gj0 + 0] + sw];
        v.y = rows[c][sh][2 * c_smp[gj0 + 1] + sw];
        v.z = rows[c][sh][2 * c_smp[gj0 + 2] + sw];
        v.w = rows[c][sh][2 * c_smp[gj0 + 3] + sw];
        *(float4*)&xs_t[((size_t)b * NC + c1) * NM + gi * 16 + gj0] = v;
    }
    // xs_m: thread t -> mloc = t>>4, c1 group = (t&15)*4 .. +3
    {
        int mloc = t >> 4, cg = t & 15;
        int w2 = 2 * c_smp[mloc];
        float4 v;
        v.x = rows[cg][0][w2];
        v.y = rows[cg][0][w2 + 1];
        v.z = rows[cg][1][w2];
        v.w = rows[cg][1][w2 + 1];
        *(float4*)&xs_m[((size_t)b * NM + gi * 16 + mloc) * NC + cg * 4] = v;
    }
}

// ---------------------------------------------------------------------------
// Kernel 2: Z[b][k][m][o] = sum_c w[o][c][k] * xs[b][m][c]
// ---------------------------------------------------------------------------
__global__ __launch_bounds__(64) void k_z(const float* __restrict__ xs_m,
                                          const float* __restrict__ w,
                                          float* __restrict__ Z) {
    int bid = blockIdx.x;            // NB*3*16
    int mg  = bid & 15;
    int k   = (bid >> 4) % 3;
    int b   = bid / 48;
    int o   = threadIdx.x;           // 64
    float wf[64];
#pragma unroll
    for (int c = 0; c < 64; ++c) wf[c] = w[((size_t)o * 64 + c) * 3 + k];
    const float* xb = xs_m + (size_t)b * NM * NC;
    float* zb = Z + ((size_t)b * 3 + k) * NM * NC;
    for (int mm = 0; mm < 16; ++mm) {
        int m = mg * 16 + mm;
        const float* xr = xb + (size_t)m * NC;   // wave-uniform address
        float acc = 0.f;
#pragma unroll
        for (int c = 0; c < 64; ++c) acc = fmaf(wf[c], xr[c], acc);
        zb[(size_t)m * NC + o] = acc;            // coalesced over o
    }
}

// ---------------------------------------------------------------------------
// Kernel 3: distances + top-3 selection.
// R6 = R3 VERBATIM except the inner dot block uses paired fma (v_pk_fma_f32
// candidate) on float2 ext-vectors. Same ds_read_b128 loads, same per-element
// fma chain order -> bitwise identical to R3. NO kc unroll pragma, NO
// prefetch (that combo caused the R4/R5 register-allocator collapse:
// VGPR 64/256 + GB-scale scratch traffic).
// ---------------------------------------------------------------------------
#define LESS_E(ad, am, bd, bm) ((ad) < (bd) || ((ad) == (bd) && (am) < (bm)))
#define INSERT_E(xd, xm)                                                        \
    do {                                                                        \
        float _xd = (xd); int _xm = (xm);                                       \
        if (LESS_E(_xd, _xm, e2d, e2m)) {                                       \
            e2d = _xd; e2m = _xm;                                               \
            if (LESS_E(e2d, e2m, e1d, e1m)) {                                   \
                float td = e1d; int tm = e1m; e1d = e2d; e1m = e2m;             \
                e2d = td; e2m = tm;                                             \
                if (LESS_E(e1d, e1m, e0d, e0m)) {                               \
                    float sd = e0d; int sm = e0m; e0d = e1d; e0m = e1m;         \
                    e1d = sd; e1m = sm;                                         \
                }                                                               \
            }                                                                   \
        }                                                                       \
    } while (0)

__global__ __launch_bounds__(256) void k_dist(const float* __restrict__ x,
                                              const float* __restrict__ xs_t,
                                              int* __restrict__ idx) {
    __shared__ __align__(16) float att[16][64];    // 4 KB   A chunk [c][n]
    __shared__ __align__(16) float xsB[16][256];   // 16 KB  B chunk [c][perm(m)]
    __shared__ float m2l[256];
    __shared__ float n2l[64];

    int b = blockIdx.x >> 6;
    int h = blockIdx.x & 63;
    int t = threadIdx.x;
    int r = t >> 5, cl = t & 31;

    v2f acc2[8][4];
#pragma unroll
    for (int i = 0; i < 8; ++i)
#pragma unroll
        for (int j = 0; j < 4; ++j) acc2[i][j] = (v2f)(0.f);

    float m2acc = 0.f, n2acc = 0.f;
    const float* xb = x + (size_t)b * 16 * 128 * 128;
    const float* xsb = xs_t + (size_t)b * NC * NM;

    for (int kc = 0; kc < 4; ++kc) {
        __syncthreads();
        // A chunk: att[c1-kc*16][w] from x with unshuffle fold. float2 covers sw={0,1}.
#pragma unroll
        for (int it = 0; it < 2; ++it) {
            int i = t + it * 256;          // 0..511
            int p = i >> 6;                // 0..7 (c1 pair within chunk)
            int wcol = i & 63;
            int c1e = kc * 16 + p * 2;
            int c = c1e >> 2, sh = (c1e >> 1) & 1;
            const float* src = xb + ((size_t)c * 128 + (2 * h + sh)) * 128 + 2 * wcol;
            float2 v = *(const float2*)src;
            att[p * 2 + 0][wcol] = v.x;
            att[p * 2 + 1][wcol] = v.y;
        }
        // B chunk: float4 coalesced from xs_t, stored to permuted halves.
#pragma unroll
        for (int it = 0; it < 4; ++it) {
            int g = t + it * 256;          // 0..1023
            int row = g >> 6;              // 0..15
            int m4 = (g & 63) * 4;         // 0,4,..,252
            int dst = ((m4 & 4) ? 128 : 0) + (m4 >> 3) * 4;
            *(float4*)&xsB[row][dst] =
                *(const float4*)&xsb[(size_t)(kc * 16 + row) * NM + m4];
        }
        __syncthreads();

        // m2 / n2 partials (sequential ascending c, mul then add like np).
#pragma unroll
        for (int c = 0; c < 16; ++c) {
            float v = xsB[c][t];
            m2acc = __fadd_rn(m2acc, __fmul_rn(v, v));
        }
        if (t < 64) {
#pragma unroll
            for (int c = 0; c < 16; ++c) {
                float v = att[c][t];
                n2acc = __fadd_rn(n2acc, __fmul_rn(v, v));
            }
        }

        // dot accumulation: 8 tokens x 4 sample-pairs, paired fma.
#pragma unroll
        for (int k = 0; k < 16; ++k) {
            float4 a0 = *(const float4*)&att[k][r * 8];
            float4 a1 = *(const float4*)&att[k][r * 8 + 4];
            float4 b0 = *(const float4*)&xsB[k][cl * 4];        // samples m0..m3
            float4 b1 = *(const float4*)&xsB[k][128 + cl * 4];  // samples m4..m7
            v2f bp0 = {b0.x, b0.y}, bp1 = {b0.z, b0.w};
            v2f bp2 = {b1.x, b1.y}, bp3 = {b1.z, b1.w};
            float aa[8] = {a0.x, a0.y, a0.z, a0.w, a1.x, a1.y, a1.z, a1.w};
#pragma unroll
            for (int i = 0; i < 8; ++i) {
                v2f ai = {aa[i], aa[i]};
                acc2[i][0] = __builtin_elementwise_fma(ai, bp0, acc2[i][0]);
                acc2[i][1] = __builtin_elementwise_fma(ai, bp1, acc2[i][1]);
                acc2[i][2] = __builtin_elementwise_fma(ai, bp2, acc2[i][2]);
                acc2[i][3] = __builtin_elementwise_fma(ai, bp3, acc2[i][3]);
            }
        }
    }

    // inverse column permutation for the m2 store
    {
        int half = t >> 7, a = (t & 127) >> 2, j = t & 3;
        m2l[a * 8 + half * 4 + j] = m2acc;
    }
    if (t < 64) n2l[t] = n2acc;
    __syncthreads();

    // preload this thread's 8 m2 values once
    float m2r[8];
#pragma unroll
    for (int j = 0; j < 8; ++j) m2r[j] = m2l[cl * 8 + j];

    // selection — fully unrolled so acc stays in VGPRs.
#pragma unroll
    for (int i = 0; i < 8; ++i) {
        int nloc = r * 8 + i;
        float n2v = n2l[nloc];
        float e0d = FLT_MAX, e1d = FLT_MAX, e2d = FLT_MAX;
        int e0m = 0x7fffffff, e1m = 0x7fffffff, e2m = 0x7fffffff;
#pragma unroll
        for (int j = 0; j < 8; ++j) {
            int m = cl * 8 + j;
            float dv = acc2[i][j >> 1][j & 1];          // compile-time indices
            float t1 = __fadd_rn(n2v, m2r[j]);          // n2 + m2
            float d = __fadd_rn(t1, -2.0f * dv);        // - 2*dot (2*acc exact)
            INSERT_E(d, m);
        }
#pragma unroll
        for (int mask = 1; mask <= 16; mask <<= 1) {
            float f0 = __shfl_xor(e0d, mask); int g0 = __shfl_xor(e0m, mask);
            float f1 = __shfl_xor(e1d, mask); int g1 = __shfl_xor(e1m, mask);
            float f2 = __shfl_xor(e2d, mask); int g2 = __shfl_xor(e2m, mask);
            INSERT_E(f0, g0);
            INSERT_E(f1, g1);
            INSERT_E(f2, g2);
        }
        if (cl == 0) {
            int n = h * 64 + nloc;
            int* op = idx + ((size_t)b * NTOK + n) * NK;
            op[0] = e0m; op[1] = e1m; op[2] = e2m;
        }
    }
}

// ---------------------------------------------------------------------------
// Kernel 4: out = bias + Z[...,idx0,:] + Z[...,idx1,:] + Z[...,idx2,:],
// pixel-shuffled.
// ---------------------------------------------------------------------------
__global__ __launch_bounds__(256) void k_out(const float* __restrict__ Z,
                                             const int* __restrict__ idx,
                                             const float* __restrict__ bias,
                                             float* __restrict__ out) {
    __shared__ float staged[64 * 65];
    int b = blockIdx.x >> 6, h = blockIdx.x & 63;
    int t = threadIdx.x;
    int o = t & 63, wv = t >> 6;
    float bv = bias[o];
    const float* zb = Z + (size_t)b * 3 * NM * NC;
    const int* ib = idx + (size_t)b * NTOK * NK;
    for (int ti = 0; ti < 16; ++ti) {
        int w = wv * 16 + ti;
        int n = h * 64 + w;
        const int* ip = ib + (size_t)n * NK;       // wave-uniform
        int i0 = ip[0], i1 = ip[1], i2 = ip[2];
        float v = bv + zb[(size_t)i0 * NC + o]
                     + zb[(size_t)(NM + i1) * NC + o]
                     + zb[(size_t)(2 * NM + i2) * NC + o];
        staged[o * 65 + w] = v;                    // (o+w)%32 banks: conflict-free
    }
    __syncthreads();
    float* ob = out + (size_t)b * 16 * 128 * 128;
#pragma unroll
    for (int it = 0; it < 16; ++it) {
        int flat = t + it * 256;                   // 0..4095
        int W = flat & 127, sh = (flat >> 7) & 1, cc = flat >> 8;
        int oo = cc * 4 + sh * 2 + (W & 1);
        ob[((size_t)cc * 128 + 2 * h + sh) * 128 + W] = staged[oo * 65 + (W >> 1)];
    }
}

// ---------------------------------------------------------------------------
extern "C" void kernel_launch(void* const* d_in, const int* in_sizes, int n_in,
                              void* d_out, int out_size, void* d_ws, size_t ws_size,
                              hipStream_t stream) {
    const float* x    = (const float*)d_in[0];
    const float* w    = (const float*)d_in[1];
    const float* bias = (const float*)d_in[2];
    float* out = (float*)d_out;
    float* ws  = (float*)d_ws;

    // workspace layout (floats):
    float* xs_t = ws;                          // 32*64*256   = 524288
    float* xs_m = ws + 524288;                 // 32*256*64   = 524288
    float* Z    = ws + 1048576;                // 32*3*256*64 = 1572864
    int*   idxb = (int*)(ws + 2621440);        // 32*4096*3   = 393216 ints
    // total ~12 MB

    hipLaunchKernelGGL(k_xs,   dim3(NB * 16),     dim3(256), 0, stream, x, xs_t, xs_m);
    hipLaunchKernelGGL(k_z,    dim3(NB * 3 * 16), dim3(64),  0, stream, xs_m, w, Z);
    hipLaunchKernelGGL(k_dist, dim3(NB * 64),     dim3(256), 0, stream, x, xs_t, idxb);
    hipLaunchKernelGGL(k_out,  dim3(NB * 64),     dim3(256), 0, stream, Z, idxb, bias, out);
}

// Round 7
// 229.670 us; speedup vs baseline: 20.7478x; 1.0331x over previous
//
#include <hip/hip_runtime.h>
#include <cstdint>
#include <cfloat>

typedef float v2f __attribute__((ext_vector_type(2)));

// Sample grid: round(linspace(0,63,16)) -- verified no .5 cases, fp32/fp64 agree.
__constant__ int c_smp[16] = {0,4,8,13,17,21,25,29,34,38,42,46,50,55,59,63};

// Problem constants
static constexpr int NB   = 32;    // batch
static constexpr int NC   = 64;    // C1 channels after unshuffle
static constexpr int NH   = 64;    // H1
static constexpr int NTOK = 4096;  // H1*W1
static constexpr int NM   = 256;   // samples
static constexpr int NK   = 3;     // neighbors

// ---------------------------------------------------------------------------
// Kernel 0: weight transpose. w[o][c][k] (innermost k, stride-3 reads for a
// fixed k-slice) -> wT[k][c][o] so k_z's per-lane (o) preload is coalesced.
// 12288 floats; linear coalesced read, scattered 4B writes (trivial size).
// ---------------------------------------------------------------------------
__global__ __launch_bounds__(256) void k_wt(const float* __restrict__ w,
                                            float* __restrict__ wT) {
    int f = blockIdx.x * 256 + threadIdx.x;      // 0..12287
    float v = w[f];
    int o = f / 192, rem = f % 192;
    int c = rem / 3, k = rem % 3;
    wT[((size_t)k * 64 + c) * 64 + o] = v;
}

// ---------------------------------------------------------------------------
// Kernel 1: gather x_sample in two layouts. One block per (b, gi).
// ---------------------------------------------------------------------------
__global__ __launch_bounds__(256) void k_xs(const float* __restrict__ x,
                                            float* __restrict__ xs_t,
                                            float* __restrict__ xs_m) {
    __shared__ __align__(16) float rows[16][2][128];   // 16 KB
    int b = blockIdx.x >> 4, gi = blockIdx.x & 15;
    int hh = c_smp[gi];
    int t = threadIdx.x;
    const float* xb = x + (size_t)b * 16 * 128 * 128;
#pragma unroll
    for (int it = 0; it < 4; ++it) {
        int q = t + it * 256;          // 0..1023 float4 groups
        int c = q >> 6;
        int rem = q & 63;
        int sh = rem >> 5;
        int col = (rem & 31) * 4;
        float4 v = *(const float4*)(xb + ((size_t)c * 128 + (2 * hh + sh)) * 128 + col);
        *(float4*)&rows[c][sh][col] = v;
    }
    __syncthreads();
    // xs_t: thread t -> c1 = t>>2, gj group = (t&3)*4 .. +3
    {
        int c1 = t >> 2;
        int c = c1 >> 2, sh = (c1 >> 1) & 1, sw = c1 & 1;
        int gj0 = (t & 3) * 4;
        float4 v;
        v.x = rows[c][sh][2 * c_smp[gj0 + 0] + sw];
        v.y = rows[c][sh][2 * c_smp[gj0 + 1] + sw];
        v.z = rows[c][sh][2 * c_smp[gj0 + 2] + sw];
        v.w = rows[c][sh][2 * c_smp[gj0 + 3] + sw];
        *(float4*)&xs_t[((size_t)b * NC + c1) * NM + gi * 16 + gj0] = v;
    }
    // xs_m: thread t -> mloc = t>>4, c1 group = (t&15)*4 .. +3
    {
        int mloc = t >> 4, cg = t & 15;
        int w2 = 2 * c_smp[mloc];
        float4 v;
        v.x = rows[cg][0][w2];
        v.y = rows[cg][0][w2 + 1];
        v.z = rows[cg][1][w2];
        v.w = rows[cg][1][w2 + 1];
        *(float4*)&xs_m[((size_t)b * NM + gi * 16 + mloc) * NC + cg * 4] = v;
    }
}

// ---------------------------------------------------------------------------
// Kernel 2: Z[b][k][m][o] = sum_c wT[k][c][o] * xs[b][m][c]
// R7: weight preload now reads wT -> lane-contiguous (coalesced). Values,
// fma order, stores identical to R6 -> Z bitwise identical.
// ---------------------------------------------------------------------------
__global__ __launch_bounds__(64) void k_z(const float* __restrict__ xs_m,
                                          const float* __restrict__ wT,
                                          float* __restrict__ Z) {
    int bid = blockIdx.x;            // NB*3*16
    int mg  = bid & 15;
    int k   = (bid >> 4) % 3;
    int b   = bid / 48;
    int o   = threadIdx.x;           // 64
    float wf[64];
#pragma unroll
    for (int c = 0; c < 64; ++c) wf[c] = wT[((size_t)k * 64 + c) * 64 + o];
    const float* xb = xs_m + (size_t)b * NM * NC;
    float* zb = Z + ((size_t)b * 3 + k) * NM * NC;
    for (int mm = 0; mm < 16; ++mm) {
        int m = mg * 16 + mm;
        const float* xr = xb + (size_t)m * NC;   // wave-uniform address
        float acc = 0.f;
#pragma unroll
        for (int c = 0; c < 64; ++c) acc = fmaf(wf[c], xr[c], acc);
        zb[(size_t)m * NC + o] = acc;            // coalesced over o
    }
}

// ---------------------------------------------------------------------------
// Kernel 3: distances + top-3 selection. R6 structure (130 us, VGPR=60,
// zero scratch): pk-fma dot tile, conflict-free permuted B layout, no kc
// unroll / no prefetch (R4/R5 post-mortem: that combo explodes live ranges).
// ---------------------------------------------------------------------------
#define LESS_E(ad, am, bd, bm) ((ad) < (bd) || ((ad) == (bd) && (am) < (bm)))
#define INSERT_E(xd, xm)                                                        \
    do {                                                                        \
        float _xd = (xd); int _xm = (xm);                                       \
        if (LESS_E(_xd, _xm, e2d, e2m)) {                                       \
            e2d = _xd; e2m = _xm;                                               \
            if (LESS_E(e2d, e2m, e1d, e1m)) {                                   \
                float td = e1d; int tm = e1m; e1d = e2d; e1m = e2m;             \
                e2d = td; e2m = tm;                                             \
                if (LESS_E(e1d, e1m, e0d, e0m)) {                               \
                    float sd = e0d; int sm = e0m; e0d = e1d; e0m = e1m;         \
                    e1d = sd; e1m = sm;                                         \
                }                                                               \
            }                                                                   \
        }                                                                       \
    } while (0)

__global__ __launch_bounds__(256) void k_dist(const float* __restrict__ x,
                                              const float* __restrict__ xs_t,
                                              int* __restrict__ idx) {
    __shared__ __align__(16) float att[16][64];    // 4 KB   A chunk [c][n]
    __shared__ __align__(16) float xsB[16][256];   // 16 KB  B chunk [c][perm(m)]
    __shared__ float m2l[256];
    __shared__ float n2l[64];

    int b = blockIdx.x >> 6;
    int h = blockIdx.x & 63;
    int t = threadIdx.x;
    int r = t >> 5, cl = t & 31;

    v2f acc2[8][4];
#pragma unroll
    for (int i = 0; i < 8; ++i)
#pragma unroll
        for (int j = 0; j < 4; ++j) acc2[i][j] = (v2f)(0.f);

    float m2acc = 0.f, n2acc = 0.f;
    const float* xb = x + (size_t)b * 16 * 128 * 128;
    const float* xsb = xs_t + (size_t)b * NC * NM;

    for (int kc = 0; kc < 4; ++kc) {
        __syncthreads();
        // A chunk: att[c1-kc*16][w] from x with unshuffle fold. float2 covers sw={0,1}.
#pragma unroll
        for (int it = 0; it < 2; ++it) {
            int i = t + it * 256;          // 0..511
            int p = i >> 6;                // 0..7 (c1 pair within chunk)
            int wcol = i & 63;
            int c1e = kc * 16 + p * 2;
            int c = c1e >> 2, sh = (c1e >> 1) & 1;
            const float* src = xb + ((size_t)c * 128 + (2 * h + sh)) * 128 + 2 * wcol;
            float2 v = *(const float2*)src;
            att[p * 2 + 0][wcol] = v.x;
            att[p * 2 + 1][wcol] = v.y;
        }
        // B chunk: float4 coalesced from xs_t, stored to permuted halves.
#pragma unroll
        for (int it = 0; it < 4; ++it) {
            int g = t + it * 256;          // 0..1023
            int row = g >> 6;              // 0..15
            int m4 = (g & 63) * 4;         // 0,4,..,252
            int dst = ((m4 & 4) ? 128 : 0) + (m4 >> 3) * 4;
            *(float4*)&xsB[row][dst] =
                *(const float4*)&xsb[(size_t)(kc * 16 + row) * NM + m4];
        }
        __syncthreads();

        // m2 / n2 partials (sequential ascending c, mul then add like np).
#pragma unroll
        for (int c = 0; c < 16; ++c) {
            float v = xsB[c][t];
            m2acc = __fadd_rn(m2acc, __fmul_rn(v, v));
        }
        if (t < 64) {
#pragma unroll
            for (int c = 0; c < 16; ++c) {
                float v = att[c][t];
                n2acc = __fadd_rn(n2acc, __fmul_rn(v, v));
            }
        }

        // dot accumulation: 8 tokens x 4 sample-pairs, paired fma.
#pragma unroll
        for (int k = 0; k < 16; ++k) {
            float4 a0 = *(const float4*)&att[k][r * 8];
            float4 a1 = *(const float4*)&att[k][r * 8 + 4];
            float4 b0 = *(const float4*)&xsB[k][cl * 4];        // samples m0..m3
            float4 b1 = *(const float4*)&xsB[k][128 + cl * 4];  // samples m4..m7
            v2f bp0 = {b0.x, b0.y}, bp1 = {b0.z, b0.w};
            v2f bp2 = {b1.x, b1.y}, bp3 = {b1.z, b1.w};
            float aa[8] = {a0.x, a0.y, a0.z, a0.w, a1.x, a1.y, a1.z, a1.w};
#pragma unroll
            for (int i = 0; i < 8; ++i) {
                v2f ai = {aa[i], aa[i]};
                acc2[i][0] = __builtin_elementwise_fma(ai, bp0, acc2[i][0]);
                acc2[i][1] = __builtin_elementwise_fma(ai, bp1, acc2[i][1]);
                acc2[i][2] = __builtin_elementwise_fma(ai, bp2, acc2[i][2]);
                acc2[i][3] = __builtin_elementwise_fma(ai, bp3, acc2[i][3]);
            }
        }
    }

    // inverse column permutation for the m2 store
    {
        int half = t >> 7, a = (t & 127) >> 2, j = t & 3;
        m2l[a * 8 + half * 4 + j] = m2acc;
    }
    if (t < 64) n2l[t] = n2acc;
    __syncthreads();

    // preload this thread's 8 m2 values once
    float m2r[8];
#pragma unroll
    for (int j = 0; j < 8; ++j) m2r[j] = m2l[cl * 8 + j];

    // selection — fully unrolled so acc stays in VGPRs.
#pragma unroll
    for (int i = 0; i < 8; ++i) {
        int nloc = r * 8 + i;
        float n2v = n2l[nloc];
        float e0d = FLT_MAX, e1d = FLT_MAX, e2d = FLT_MAX;
        int e0m = 0x7fffffff, e1m = 0x7fffffff, e2m = 0x7fffffff;
#pragma unroll
        for (int j = 0; j < 8; ++j) {
            int m = cl * 8 + j;
            float dv = acc2[i][j >> 1][j & 1];          // compile-time indices
            float t1 = __fadd_rn(n2v, m2r[j]);          // n2 + m2
            float d = __fadd_rn(t1, -2.0f * dv);        // - 2*dot (2*acc exact)
            INSERT_E(d, m);
        }
#pragma unroll
        for (int mask = 1; mask <= 16; mask <<= 1) {
            float f0 = __shfl_xor(e0d, mask); int g0 = __shfl_xor(e0m, mask);
            float f1 = __shfl_xor(e1d, mask); int g1 = __shfl_xor(e1m, mask);
            float f2 = __shfl_xor(e2d, mask); int g2 = __shfl_xor(e2m, mask);
            INSERT_E(f0, g0);
            INSERT_E(f1, g1);
            INSERT_E(f2, g2);
        }
        if (cl == 0) {
            int n = h * 64 + nloc;
            int* op = idx + ((size_t)b * NTOK + n) * NK;
            op[0] = e0m; op[1] = e1m; op[2] = e2m;
        }
    }
}

// ---------------------------------------------------------------------------
// Kernel 4: out = bias + Z[...,idx0,:] + Z[...,idx1,:] + Z[...,idx2,:],
// pixel-shuffled.
// ---------------------------------------------------------------------------
__global__ __launch_bounds__(256) void k_out(const float* __restrict__ Z,
                                             const int* __restrict__ idx,
                                             const float* __restrict__ bias,
                                             float* __restrict__ out) {
    __shared__ float staged[64 * 65];
    int b = blockIdx.x >> 6, h = blockIdx.x & 63;
    int t = threadIdx.x;
    int o = t & 63, wv = t >> 6;
    float bv = bias[o];
    const float* zb = Z + (size_t)b * 3 * NM * NC;
    const int* ib = idx + (size_t)b * NTOK * NK;
    for (int ti = 0; ti < 16; ++ti) {
        int w = wv * 16 + ti;
        int n = h * 64 + w;
        const int* ip = ib + (size_t)n * NK;       // wave-uniform
        int i0 = ip[0], i1 = ip[1], i2 = ip[2];
        float v = bv + zb[(size_t)i0 * NC + o]
                     + zb[(size_t)(NM + i1) * NC + o]
                     + zb[(size_t)(2 * NM + i2) * NC + o];
        staged[o * 65 + w] = v;                    // (o+w)%32 banks: conflict-free
    }
    __syncthreads();
    float* ob = out + (size_t)b * 16 * 128 * 128;
#pragma unroll
    for (int it = 0; it < 16; ++it) {
        int flat = t + it * 256;                   // 0..4095
        int W = flat & 127, sh = (flat >> 7) & 1, cc = flat >> 8;
        int oo = cc * 4 + sh * 2 + (W & 1);
        ob[((size_t)cc * 128 + 2 * h + sh) * 128 + W] = staged[oo * 65 + (W >> 1)];
    }
}

// ---------------------------------------------------------------------------
extern "C" void kernel_launch(void* const* d_in, const int* in_sizes, int n_in,
                              void* d_out, int out_size, void* d_ws, size_t ws_size,
                              hipStream_t stream) {
    const float* x    = (const float*)d_in[0];
    const float* w    = (const float*)d_in[1];
    const float* bias = (const float*)d_in[2];
    float* out = (float*)d_out;
    float* ws  = (float*)d_ws;

    // workspace layout (floats):
    float* xs_t = ws;                          // 32*64*256   = 524288
    float* xs_m = ws + 524288;                 // 32*256*64   = 524288
    float* Z    = ws + 1048576;                // 32*3*256*64 = 1572864
    int*   idxb = (int*)(ws + 2621440);        // 32*4096*3   = 393216 ints
    float* wT   = ws + 3014656;                // 3*64*64     = 12288
    // total ~12.1 MB

    hipLaunchKernelGGL(k_wt,   dim3(48),          dim3(256), 0, stream, w, wT);
    hipLaunchKernelGGL(k_xs,   dim3(NB * 16),     dim3(256), 0, stream, x, xs_t, xs_m);
    hipLaunchKernelGGL(k_z,    dim3(NB * 3 * 16), dim3(64),  0, stream, xs_m, wT, Z);
    hipLaunchKernelGGL(k_dist, dim3(NB * 64),     dim3(256), 0, stream, x, xs_t, idxb);
    hipLaunchKernelGGL(k_out,  dim3(NB * 64),     dim3(256), 0, stream, Z, idxb, bias, out);
}